// Round 4
// baseline (406.904 us; speedup 1.0000x reference)
//
#include <hip/hip_runtime.h>
#include <hip/hip_bf16.h>

using f16 = _Float16;
typedef __attribute__((ext_vector_type(8))) f16 half8;
typedef __attribute__((ext_vector_type(4))) f16 half4;
typedef __attribute__((ext_vector_type(4))) float floatx4;

#define LN_EPS 1e-5f

// ---------------------------------------------------------------------------
// async global->LDS, 16B per lane. LDS dest is wave-uniform base + lane*16.
// ---------------------------------------------------------------------------
__device__ __forceinline__ void gload_lds16(const f16* g, f16* l) {
  __builtin_amdgcn_global_load_lds(
      (const __attribute__((address_space(1))) void*)g,
      (__attribute__((address_space(3))) void*)l, 16, 0, 0);
}

#define CFENCE asm volatile("" ::: "memory")
#define WAIT_VM(N) asm volatile("s_waitcnt vmcnt(" #N ")" ::: "memory")
#define BARRIER()                    \
  do {                               \
    CFENCE;                          \
    __builtin_amdgcn_s_barrier();    \
    CFENCE;                          \
  } while (0)

// ---------------------------------------------------------------------------
// 256x256-tile 8-phase pipelined GEMM core (T1+T2+T3+T4+T5), 512 thr
// (8 waves, 2Mx4N), BK=64, per-wave output 128x64 (acc[8][4] f32x4),
// 128 KiB LDS (2 K-tile buffers x (A 256x64 + B 256x64) f16).
// Schedule identical to the round-1 harness-verified kernel.
// ---------------------------------------------------------------------------
template <int EPI>
__device__ __forceinline__ void gemm256_core(
    const f16* __restrict__ A, const f16* __restrict__ B,
    f16* __restrict__ Cz, const float* __restrict__ bias,
    int lda, int ldb, int ldc, int kper, int kbeg, int bm, int bn,
    f16* smp) {
  const int t = threadIdx.x;
  const int wave = t >> 6, lane = t & 63;
  const int wm = (wave >> 2) << 7;  // wave M offset: 0/128
  const int wn = (wave & 3) << 6;   // wave N offset: 0/64/128/192
  const int lrow = lane & 15, lkc = lane >> 4;

  // staging: seg = wave*2+l covers 8 rows of a 128-row half-tile
  const int srow = lane >> 3;
  const int schunk = ((lane & 7) ^ srow) << 3;  // swizzled source chunk (elems)
  const f16* Ag = A + (size_t)(bm + wave * 16 + srow) * lda + kbeg + schunk;
  const f16* Bg = B + (size_t)(bn + wave * 16 + srow) * ldb + kbeg + schunk;

  // swizzled fragment k-offsets (elems within 64-elem row), kk = 0 / 1
  const int co0 = ((lkc ^ (lrow & 7)) << 3);
  const int co1 = (((4 + lkc) ^ (lrow & 7)) << 3);

  floatx4 acc[8][4] = {};
  half8 af[4][2];       // one qm-half of A frags, both kk
  half8 bf[2][2][2];    // [qn][fn][kk] -- both qn halves live

  auto STAGE = [&](int b, int tt, int h) {  // h: 0=A-lo 1=A-hi 2=B-lo 3=B-hi
    if (h < 2) {
      const f16* src = Ag + (size_t)(h * 128) * lda + tt * 64;
      f16* d = smp + (b * 2) * 16384 + h * 8192 + wave * 1024;
      gload_lds16(src, d);
      gload_lds16(src + (size_t)8 * lda, d + 512);
    } else {
      const f16* src = Bg + (size_t)((h - 2) * 128) * ldb + tt * 64;
      f16* d = smp + (b * 2 + 1) * 16384 + (h - 2) * 8192 + wave * 1024;
      gload_lds16(src, d);
      gload_lds16(src + (size_t)8 * ldb, d + 512);
    }
  };
  auto LDA = [&](int b, int qm) {
    const f16* base = smp + (b * 2) * 16384 + (wm + qm * 64 + lrow) * 64;
#pragma unroll
    for (int fm = 0; fm < 4; ++fm) {
      af[fm][0] = *(const half8*)(base + fm * (16 * 64) + co0);
      af[fm][1] = *(const half8*)(base + fm * (16 * 64) + co1);
    }
  };
  auto LDB = [&](int b, int qn) {
    const f16* base = smp + (b * 2 + 1) * 16384 + (wn + qn * 32 + lrow) * 64;
#pragma unroll
    for (int fn = 0; fn < 2; ++fn) {
      bf[qn][fn][0] = *(const half8*)(base + fn * (16 * 64) + co0);
      bf[qn][fn][1] = *(const half8*)(base + fn * (16 * 64) + co1);
    }
  };
  auto MFMAQ = [&](int qm, int qn) {
    __builtin_amdgcn_s_setprio(1);
#pragma unroll
    for (int kk = 0; kk < 2; ++kk)
#pragma unroll
      for (int fm = 0; fm < 4; ++fm)
#pragma unroll
        for (int fn = 0; fn < 2; ++fn)
          acc[qm * 4 + fm][qn * 2 + fn] =
              __builtin_amdgcn_mfma_f32_16x16x32_f16(
                  af[fm][kk], bf[qn][fn][kk], acc[qm * 4 + fm][qn * 2 + fn],
                  0, 0, 0);
    __builtin_amdgcn_s_setprio(0);
  };

  const int NT = kper >> 6;  // K-tiles (even for all call sites)
  const int NI = NT >> 1;

  // prologue: tile0 -> buf0 (4 halves), tile1 half0 -> buf1; wait tile0
  STAGE(0, 0, 0); STAGE(0, 0, 1); STAGE(0, 0, 2); STAGE(0, 0, 3);
  STAGE(1, 1, 0);
  WAIT_VM(2);
  BARRIER();

  for (int i = 0; i < NI; ++i) {
    const bool last = (i == NI - 1);
    const int tb = 2 * i;
    // P0 -- t0 Q(0,0)
    LDA(0, 0); LDB(0, 0); STAGE(1, tb + 1, 1);
    BARRIER(); MFMAQ(0, 0); BARRIER();
    // P1 -- t0 Q(0,1)
    LDB(0, 1); STAGE(1, tb + 1, 2);
    BARRIER(); MFMAQ(0, 1); BARRIER();
    // P2 -- t0 Q(1,0)
    LDA(0, 1); STAGE(1, tb + 1, 3);
    BARRIER(); MFMAQ(1, 0); BARRIER();
    // P3 -- t0 Q(1,1); guarantee tile t1 landed before P4 reads buf1
    if (!last) {
      STAGE(0, tb + 2, 0);
      WAIT_VM(2);
    } else {
      WAIT_VM(0);
    }
    BARRIER(); MFMAQ(1, 1); BARRIER();
    // P4 -- t1 Q(0,0)
    LDA(1, 0); LDB(1, 0);
    if (!last) STAGE(0, tb + 2, 1);
    BARRIER(); MFMAQ(0, 0); BARRIER();
    // P5 -- t1 Q(0,1)
    LDB(1, 1);
    if (!last) STAGE(0, tb + 2, 2);
    BARRIER(); MFMAQ(0, 1); BARRIER();
    // P6 -- t1 Q(1,0)
    LDA(1, 1);
    if (!last) STAGE(0, tb + 2, 3);
    BARRIER(); MFMAQ(1, 0); BARRIER();
    // P7 -- t1 Q(1,1); guarantee tile t0+2 landed before next P0 reads buf0
    if (!last) {
      STAGE(1, tb + 3, 0);
      WAIT_VM(2);
    }
    BARRIER(); MFMAQ(1, 1); BARRIER();
  }

  // epilogue: C/D col = lane&15, row = (lane>>4)*4 + reg
  const int crow0 = bm + wm + lkc * 4;
  const int ccol0 = bn + wn + lrow;
#pragma unroll
  for (int i = 0; i < 8; ++i) {
#pragma unroll
    for (int r2 = 0; r2 < 4; ++r2) {
      const size_t row = (size_t)(crow0 + i * 16 + r2);
#pragma unroll
      for (int j = 0; j < 4; ++j) {
        const int col = ccol0 + j * 16;
        float v = acc[i][j][r2];
        if (EPI == 2) v = fmaxf(v + bias[col], 0.0f);
        Cz[row * (size_t)ldc + col] = (f16)v;
      }
    }
  }
}

// bijective XCD-chunked swizzle (T1): block with HW id `id` (XCD = id%8)
// computes tile nid from its XCD's contiguous chunk.
__device__ __forceinline__ int xcd_swizzle(int id, int nwg) {
  const int q = nwg >> 3, r = nwg & 7;
  const int xcd = id & 7, lin = id >> 3;
  return (xcd < r ? xcd * (q + 1) : r * (q + 1) + (xcd - r) * q) + lin;
}

// ---------------------------------------------------------------------------
// generic NT wrapper: C = A*B^T, split-K via gridDim.z, f16 slabs at
// Ch + z*M*ldc.
// ---------------------------------------------------------------------------
template <int EPI>
__global__ __launch_bounds__(512, 2) void gemm_nt256(
    const f16* __restrict__ A, const f16* __restrict__ B,
    f16* __restrict__ Ch, const float* __restrict__ bias,
    int M, int Nc, int K, int lda, int ldb, int ldc) {
  __shared__ f16 sm[4][256 * 64];
  const int gx = gridDim.x, gy = gridDim.y;
  const int nwg = gx * gy * gridDim.z;
  const int id = blockIdx.x + gx * (blockIdx.y + gy * blockIdx.z);
  const int nid = xcd_swizzle(id, nwg);
  const int bx = nid % gx;
  const int by = (nid / gx) % gy;
  const int bz = nid / (gx * gy);
  const int kper = K / gridDim.z;
  gemm256_core<EPI>(A, B, Ch + (size_t)bz * M * ldc, bias, lda, ldb, ldc,
                    kper, bz * kper, by << 8, bx << 8, &sm[0][0]);
}

// ---------------------------------------------------------------------------
// weight precompose on the 8-phase core: grid (4,4,16).
// z<8: parQK slab zz = Wkb@Wqb^T (K=4096 split 8); z>=8: parVO = WoT@Wvb^T.
// ---------------------------------------------------------------------------
__global__ __launch_bounds__(512, 2) void gemm_pre256(
    const f16* __restrict__ Wkb, const f16* __restrict__ Wqb,
    const f16* __restrict__ WoT, const f16* __restrict__ Wvb,
    f16* __restrict__ parQK, f16* __restrict__ parVO, int D, int H) {
  __shared__ f16 sm[4][256 * 64];
  const int id = blockIdx.x + 4 * (blockIdx.y + 4 * blockIdx.z);
  const int nid = xcd_swizzle(id, 256);
  const int bx = nid & 3, by = (nid >> 2) & 3, z = nid >> 4;
  const int zz = z & 7;
  const f16* A = (z < 8) ? Wkb : WoT;
  const f16* B = (z < 8) ? Wqb : Wvb;
  f16* slab = ((z < 8) ? parQK : parVO) + (size_t)zz * D * D;
  gemm256_core<1>(A, B, slab, nullptr, H, H, D, H / 8, zz * (H / 8),
                  by << 8, bx << 8, &sm[0][0]);
}

// ---------------------------------------------------------------------------
// merged th/xvoT on the 8-phase core: grid (4,32).
// y<16: th = xb@WqkT^T [N,D] (bm=y,bn=x); y>=16: xvoT = WvoT@xb^T [D,N].
// ---------------------------------------------------------------------------
__global__ __launch_bounds__(512, 2) void gemm_dual256(
    const f16* __restrict__ xb, const f16* __restrict__ WqkT,
    const f16* __restrict__ WvoT, f16* __restrict__ th,
    f16* __restrict__ xvoT, int N, int D) {
  __shared__ f16 sm[4][256 * 64];
  const int id = blockIdx.x + 4 * blockIdx.y;
  const int nid = xcd_swizzle(id, 128);
  const int bx = nid & 3, y = nid >> 2;
  if (y < 16)
    gemm256_core<1>(xb, WqkT, th, nullptr, D, D, D, D, 0,
                    y << 8, bx << 8, &sm[0][0]);
  else
    gemm256_core<1>(WvoT, xb, xvoT, nullptr, D, D, N, D, 0,
                    bx << 8, (y - 16) << 8, &sm[0][0]);
}

// ---------------------------------------------------------------------------
// fused input prep, grid (1792), block 256 -- latency-depth rework.
// blocks 0..1023: converts (4 matrices x 256 blocks). Each thread: 16
//   independent float4 loads (256B in flight), then 8 half8 stores.
// blocks 1024..1791: transposes (3 matrices x 256 blocks x 4 tiles).
//   Per 64x64 tile: verified shfl-transpose (masks 32/16) + swizzled LDS
//   (r' = r ^ ((c&15)<<2)); software-pipelined: tile i+1's 4 global loads
//   issue before tile i's shuffle/store; double-buffered LDS, ONE barrier
//   per tile.
// ---------------------------------------------------------------------------
__global__ void prep_inputs(const float* x, const float* Wq, const float* Wk,
                            const float* Wv, const float* W1, const float* Wo,
                            const float* W2, f16* xb, f16* Wqb, f16* Wkb,
                            f16* Wvb, f16* W1T, f16* WoT, f16* W2T) {
  const int b = blockIdx.x;
  const int t = threadIdx.x;
  __shared__ f16 lt[2][64 * 64];
  if (b < 1024) {  // converts: 4M elems each matrix
    const int m = b >> 8;
    const float* in = (m == 0) ? x : (m == 1) ? Wq : (m == 2) ? Wk : Wv;
    f16* out = (m == 0) ? xb : (m == 1) ? Wqb : (m == 2) ? Wkb : Wvb;
    const float* ib = in + (size_t)(b & 255) * 16384;
    f16* ob = out + (size_t)(b & 255) * 16384;
    float4 ra[8], rb[8];
#pragma unroll
    for (int j = 0; j < 8; ++j) {
      ra[j] = *(const float4*)(ib + j * 2048 + t * 8);
      rb[j] = *(const float4*)(ib + j * 2048 + t * 8 + 4);
    }
#pragma unroll
    for (int j = 0; j < 8; ++j) {
      half8 v = {(f16)ra[j].x, (f16)ra[j].y, (f16)ra[j].z, (f16)ra[j].w,
                 (f16)rb[j].x, (f16)rb[j].y, (f16)rb[j].z, (f16)rb[j].w};
      *(half8*)(ob + j * 2048 + t * 8) = v;
    }
    return;
  }
  // transposes
  const int tb = b - 1024;
  const int m = tb >> 8;  // 0:W1 1:Wo 2:W2
  int R, C;
  const float* in;
  f16* out;
  if (m == 0) {
    R = 1024; C = 4096; in = W1; out = W1T;
  } else {
    R = 4096; C = 1024;
    in = (m == 1) ? Wo : W2;
    out = (m == 1) ? WoT : W2T;
  }
  const int tile0 = (tb & 255) * 4;
  const int lr = t >> 4;          // 0..15: row-chunk id
  const int lc = t & 15;          // col-chunk id (16B = 4 floats)
  const int q3 = lr & 3;          // row within 4x4 block
  const int rb_ = lr & ~3;        // 4-row block base
  const int myc = lc * 4 + q3;    // column owned after transpose
  const int oc = t >> 3, orr = (t & 7) << 3;

  auto tcoord = [&](int tile, int& r0, int& c0) {
    if (m == 0) { r0 = (tile >> 6) << 6; c0 = (tile & 63) << 6; }
    else        { r0 = (tile >> 4) << 6; c0 = (tile & 15) << 6; }
  };
  auto loadt = [&](int tile, float4* fr) {
    int r0, c0;
    tcoord(tile, r0, c0);
#pragma unroll
    for (int rr = 0; rr < 4; ++rr)
      fr[rr] =
          *(const float4*)(in + (size_t)(r0 + lr + rr * 16) * C + c0 + lc * 4);
  };

  float4 cur[4], nxt[4];
  loadt(tile0, cur);
#pragma unroll
  for (int it = 0; it < 4; ++it) {
    if (it < 3) loadt(tile0 + it + 1, nxt);
    int r0, c0;
    tcoord(tile0 + it, r0, c0);
    f16* ltb = lt[it & 1];
#pragma unroll
    for (int rr = 0; rr < 4; ++rr) {
      float v0 = cur[rr].x, v1 = cur[rr].y, v2 = cur[rr].z, v3 = cur[rr].w;
      // 4x4 transpose among lanes {t ^ 16, t ^ 32}: block swap (mask 32)...
      {
        const bool hi = (q3 & 2) != 0;
        float sA = hi ? v0 : v2;
        float sB = hi ? v1 : v3;
        sA = __shfl_xor(sA, 32);
        sB = __shfl_xor(sB, 32);
        if (hi) { v0 = sA; v1 = sB; } else { v2 = sA; v3 = sB; }
      }
      // ...then in-block 2x2 transpose (mask 16)
      {
        const bool od = (q3 & 1) != 0;
        float sC = od ? v0 : v1;
        float sD = od ? v2 : v3;
        sC = __shfl_xor(sC, 16);
        sD = __shfl_xor(sD, 16);
        if (od) { v0 = sC; v2 = sD; } else { v1 = sC; v3 = sD; }
      }
      half4 hv = {(f16)v0, (f16)v1, (f16)v2, (f16)v3};
      const int rbase = rb_ + rr * 16;
      *(half4*)(ltb + myc * 64 + (rbase ^ ((myc & 15) << 2))) = hv;
    }
    __syncthreads();
#pragma unroll
    for (int cc = 0; cc < 2; ++cc) {
      const int c = oc + cc * 32;
      const int swz = (c & 15) << 2;
      const half4 ha = *(const half4*)(ltb + c * 64 + (orr ^ swz));
      const half4 hb4 = *(const half4*)(ltb + c * 64 + ((orr + 4) ^ swz));
      half8 v = {ha[0], ha[1], ha[2], ha[3], hb4[0], hb4[1], hb4[2], hb4[3]};
      *(half8*)(out + (size_t)(c0 + c) * R + r0 + orr) = v;
    }
#pragma unroll
    for (int rr = 0; rr < 4; ++rr) cur[rr] = nxt[rr];
  }
}

// ---------------------------------------------------------------------------
// merged slab reduce: first half of blocks sum 8 f16 slabs parQK -> WqkT,
// second half parVO -> WvoT. n = D*D. 16B/lane loads.
// ---------------------------------------------------------------------------
__global__ void reduce_dual(const f16* __restrict__ parQK,
                            const f16* __restrict__ parVO,
                            f16* __restrict__ WqkT, f16* __restrict__ WvoT,
                            int n) {
  const int half = gridDim.x >> 1;
  const bool second = blockIdx.x >= half;
  const f16* par = second ? parVO : parQK;
  f16* out = second ? WvoT : WqkT;
  const int b = second ? blockIdx.x - half : blockIdx.x;
  const int i = (b * 256 + threadIdx.x) * 8;
  float s[8] = {};
#pragma unroll
  for (int z = 0; z < 8; ++z) {
    const half8 p = *(const half8*)(par + (size_t)z * n + i);
#pragma unroll
    for (int k = 0; k < 8; ++k) s[k] += (float)p[k];
  }
  half8 o = {(f16)s[0], (f16)s[1], (f16)s[2], (f16)s[3],
             (f16)s[4], (f16)s[5], (f16)s[6], (f16)s[7]};
  *(half8*)(out + i) = o;
}

// ---------------------------------------------------------------------------
// row softmax: f16 S[row,:N] -> f16 P. One 256-thread block per row, N=4096.
// ---------------------------------------------------------------------------
__global__ void softmax_rows(const f16* __restrict__ S, f16* __restrict__ P,
                             int N) {
  const int row = blockIdx.x;
  const int t = threadIdx.x;
  const int lane = t & 63, wave = t >> 6;
  const f16* s = S + (size_t)row * N;
  const half8 a = *(const half8*)(s + t * 8);
  const half8 b = *(const half8*)(s + 2048 + t * 8);
  float v[16];
#pragma unroll
  for (int i = 0; i < 8; ++i) {
    v[i] = (float)a[i];
    v[8 + i] = (float)b[i];
  }
  float mx = -1e30f;
#pragma unroll
  for (int i = 0; i < 16; ++i) mx = fmaxf(mx, v[i]);
#pragma unroll
  for (int off = 32; off > 0; off >>= 1) mx = fmaxf(mx, __shfl_xor(mx, off));
  __shared__ float red[8];
  if (lane == 0) red[wave] = mx;
  __syncthreads();
  mx = fmaxf(fmaxf(red[0], red[1]), fmaxf(red[2], red[3]));
  float sum = 0.0f;
#pragma unroll
  for (int i = 0; i < 16; ++i) {
    v[i] = __expf(v[i] - mx);
    sum += v[i];
  }
#pragma unroll
  for (int off = 32; off > 0; off >>= 1) sum += __shfl_xor(sum, off);
  if (lane == 0) red[4 + wave] = sum;
  __syncthreads();
  const float inv = 1.0f / (red[4] + red[5] + red[6] + red[7]);
  f16* p = P + (size_t)row * N;
  half8 oa, ob;
#pragma unroll
  for (int i = 0; i < 8; ++i) {
    oa[i] = (f16)(v[i] * inv);
    ob[i] = (f16)(v[8 + i] * inv);
  }
  *(half8*)(p + t * 8) = oa;
  *(half8*)(p + 2048 + t * 8) = ob;
}

// ---------------------------------------------------------------------------
// fused residual + f16 split-K slab reduce + (optional bias) + LayerNorm.
// One block per row, D=1024. b = base of nchunks f16 slabs, stride cs elems.
// ---------------------------------------------------------------------------
__global__ void add_ln(const float* __restrict__ a, const f16* __restrict__ b,
                       int nchunks, size_t cs, const float* __restrict__ bias,
                       const float* __restrict__ g, const float* __restrict__ be,
                       float* __restrict__ outf, f16* __restrict__ outh, int D) {
  const int row = blockIdx.x;
  const int t = threadIdx.x;
  const int lane = t & 63, wave = t >> 6;
  const float4 av = *(const float4*)(a + (size_t)row * D + t * 4);
  float s[4] = {av.x, av.y, av.z, av.w};
  for (int c = 0; c < nchunks; ++c) {
    const half4 bv = *(const half4*)(b + c * cs + (size_t)row * D + t * 4);
    s[0] += (float)bv[0]; s[1] += (float)bv[1];
    s[2] += (float)bv[2]; s[3] += (float)bv[3];
  }
  if (bias != nullptr) {
    const float4 bb = *(const float4*)(bias + t * 4);
    s[0] += bb.x; s[1] += bb.y; s[2] += bb.z; s[3] += bb.w;
  }
  float sum = s[0] + s[1] + s[2] + s[3];
  float sq = s[0] * s[0] + s[1] * s[1] + s[2] * s[2] + s[3] * s[3];
#pragma unroll
  for (int off = 32; off > 0; off >>= 1) {
    sum += __shfl_xor(sum, off);
    sq += __shfl_xor(sq, off);
  }
  __shared__ float red[8];
  if (lane == 0) {
    red[wave] = sum;
    red[4 + wave] = sq;
  }
  __syncthreads();
  sum = red[0] + red[1] + red[2] + red[3];
  sq = red[4] + red[5] + red[6] + red[7];
  const float mu = sum / (float)D;
  const float rv = rsqrtf(sq / (float)D - mu * mu + LN_EPS);
  const float4 gv = *(const float4*)(g + t * 4);
  const float4 bev = *(const float4*)(be + t * 4);
  float y0 = (s[0] - mu) * rv * gv.x + bev.x;
  float y1 = (s[1] - mu) * rv * gv.y + bev.y;
  float y2 = (s[2] - mu) * rv * gv.z + bev.z;
  float y3 = (s[3] - mu) * rv * gv.w + bev.w;
  if (outf != nullptr) {
    float4 o = {y0, y1, y2, y3};
    *(float4*)(outf + (size_t)row * D + t * 4) = o;
  }
  if (outh != nullptr) {
    f16* ob = outh + (size_t)row * D + t * 4;
    ob[0] = (f16)y0;
    ob[1] = (f16)y1;
    ob[2] = (f16)y2;
    ob[3] = (f16)y3;
  }
}

// ---------------------------------------------------------------------------
// launch
// ---------------------------------------------------------------------------
extern "C" void kernel_launch(void* const* d_in, const int* in_sizes, int n_in,
                              void* d_out, int out_size, void* d_ws,
                              size_t ws_size, hipStream_t stream) {
  constexpr int N = 4096, D = 1024, H = 4096;
  const float* x = (const float*)d_in[0];
  const float* Wq = (const float*)d_in[1];
  const float* Wk = (const float*)d_in[2];
  const float* Wv = (const float*)d_in[3];
  const float* Wo = (const float*)d_in[4];
  const float* W1 = (const float*)d_in[5];
  const float* b1 = (const float*)d_in[6];
  const float* W2 = (const float*)d_in[7];
  const float* b2 = (const float*)d_in[8];
  const float* g1 = (const float*)d_in[9];
  const float* be1 = (const float*)d_in[10];
  const float* g2 = (const float*)d_in[11];
  const float* be2 = (const float*)d_in[12];
  float* out = (float*)d_out;

  const size_t MB = 1024ull * 1024ull;
  char* w = (char*)d_ws;
  // workspace layout (228 MB used; hazard-checked reuse; offsets in MB):
  f16* xb   = (f16*)(w + 0 * MB);     // 8   [N,D]
  f16* Wqb  = (f16*)(w + 8 * MB);     // 8   [D,H]
  f16* Wkb  = (f16*)(w + 16 * MB);    // 8   [D,H]
  f16* Wvb  = (f16*)(w + 24 * MB);    // 8   [D,H]
  f16* WoT  = (f16*)(w + 32 * MB);    // 8   [D,H]
  f16* W1T  = (f16*)(w + 40 * MB);    // 8   [H,D]
  f16* W2T  = (f16*)(w + 48 * MB);    // 8   [D,H]
  f16* WqkT = (f16*)(w + 56 * MB);    // 2   [D,D] = (Wq@Wk^T)^T
  f16* WvoT = (f16*)(w + 58 * MB);    // 2   [D,D] = (Wv@Wo)^T
  f16* th   = (f16*)(w + 60 * MB);    // 8   [N,D]; dead after S
  f16* xvoT = (f16*)(w + 68 * MB);    // 8   [D,N]
  f16* F1   = (f16*)(w + 76 * MB);    // 32  [N,H]
  f16* Sh   = (f16*)(w + 108 * MB);   // 32  [N,N] f16; dead after softmax
  f16* parA = (f16*)(w + 108 * MB);   // 4x8MB f16 slabs (over dead Sh)
  f16* Pb   = (f16*)(w + 140 * MB);   // 32  [N,N]; dead after attn
  float* hf = (float*)(w + 172 * MB); // 16  [N,D]
  f16* hb   = (f16*)(w + 188 * MB);   // 8   [N,D]
  f16* parQK = (f16*)(w + 196 * MB);  // 16 = 8x2MB f16 slabs; dead after reduce
  f16* parVO = (f16*)(w + 212 * MB);  // 16 = 8x2MB f16 slabs; dead after reduce

  // ---- input prep: 4 converts + 3 transposes, ONE dispatch, ILP-deep ----
  prep_inputs<<<dim3(1792), 256, 0, stream>>>(
      x, Wq, Wk, Wv, W1, Wo, W2, xb, Wqb, Wkb, Wvb, W1T, WoT, W2T);

  // ---- weight precomposition (both [D,D] composites, one dispatch) ----
  gemm_pre256<<<dim3(4, 4, 16), 512, 0, stream>>>(
      Wkb, Wqb, WoT, Wvb, parQK, parVO, D, H);
  reduce_dual<<<2 * (D * D) / 2048, 256, 0, stream>>>(parQK, parVO, WqkT,
                                                      WvoT, D * D);

  // ---- attention ----
  // th = xb@WqkT^T [N,D] and xvoT = WvoT@xb^T [D,N], one dispatch
  gemm_dual256<<<dim3(4, 32), 512, 0, stream>>>(xb, WqkT, WvoT, th, xvoT,
                                                N, D);
  // S = th @ xb^T  [N,N] f16 logits (K=1024), 256^2 8-phase kernel
  gemm_nt256<1><<<dim3(N / 256, N / 256, 1), 512, 0, stream>>>(
      th, xb, Sh, nullptr, N, N, D, D, D, N);
  softmax_rows<<<N, 256, 0, stream>>>(Sh, Pb, N);
  // attn partials = Pb @ xvoT^T  [N,D], split-K=4, f16 slabs (over dead Sh)
  gemm_nt256<1><<<dim3(D / 256, N / 256, 4), 512, 0, stream>>>(
      Pb, xvoT, parA, nullptr, N, D, N, N, N, D);
  // h = LN(x + sum(attn partials))
  add_ln<<<N, 256, 0, stream>>>(x, parA, 4, (size_t)N * D, nullptr, g1, be1,
                                hf, hb, D);

  // ---- feed-forward ----
  // F1 = relu(hb @ W1T^T + b1)  [N,H] f16
  gemm_nt256<2><<<dim3(H / 256, N / 256, 1), 512, 0, stream>>>(
      hb, W1T, F1, b1, N, H, D, D, D, H);
  // F2 partials = F1 @ W2T^T  [N,D], split-K=4, f16 slabs
  gemm_nt256<1><<<dim3(D / 256, N / 256, 4), 512, 0, stream>>>(
      F1, W2T, parA, nullptr, N, D, H, H, H, D);
  // out = LN(hf + sum(F2 partials) + b2)
  add_ln<<<N, 256, 0, stream>>>(hf, parA, 4, (size_t)N * D, b2, g2, be2,
                                out, nullptr, D);
}